// Round 2
// baseline (983.936 us; speedup 1.0000x reference)
//
#include <hip/hip_runtime.h>
#include <hip/hip_bf16.h>

// ContextualEncoder2: 5 GRU cells, N=16384, H=1024, INPUT=1088. fp32 in/out (per reference);
// compute in bf16 MFMA with fp32 accumulate (threshold = 2% of max|ref| = 1.47e-2).
// Algebraic restructure:
//   steps 0-2: gi = obs_t @ Wih[:, :64]^T + E[id]  where E = emb @ Wih[:,64:]^T + b_ih (100 ids, fp32)
//   steps 3-4: gi = [h | obs_t] @ Wih^T + b_ih   (h stored in 1088-wide padded bf16 buffer)
//   gates fused into GEMM epilogue with 4 accum quantities: r_sum, z_sum, gi_n, gh_n.

typedef __bf16 bf16_4 __attribute__((ext_vector_type(4)));
typedef __bf16 bf16_8 __attribute__((ext_vector_type(8)));
typedef float  f32_16 __attribute__((ext_vector_type(16)));

#define NBUOY 16384
#define HID   1024

__device__ __forceinline__ void async16(const void* g, void* l) {
    __builtin_amdgcn_global_load_lds(
        (const __attribute__((address_space(1))) unsigned int*)g,
        (__attribute__((address_space(3))) unsigned int*)l, 16, 0, 0);
}
__device__ __forceinline__ float sigm(float x)  { return 1.f / (1.f + __expf(-x)); }
__device__ __forceinline__ float tanh_f(float x){ return 1.f - 2.f / (1.f + __expf(2.f * x)); }

// One K-phase of the fused GRU GEMM. QN = acc index for this phase's "n" contribution
// (2 = gi_n for IH phase, 3 = gh_n for HH phase).
// LDS layout: row-major, 64 cols (128B rows); 16B chunks XOR-swizzled by (row&7) on the
// GLOBAL side (global_load_lds forces lds dst = wave base + lane*16).
template<int QN, int K>
__device__ __forceinline__ void phase_loop(
    const __bf16* __restrict__ Ap, long sA, int aRow0,
    const __bf16* __restrict__ Wp, long sW, int n0,
    __bf16* lsA, __bf16* lsB, f32_16 acc[4][2], int tid)
{
    const int lane = tid & 63, wid = tid >> 6;
    const int wm = wid >> 1, wn = wid & 1;
    const int l31 = lane & 31, hi = lane >> 5, l7 = lane & 7;
    const int srow = tid >> 3, schunk = tid & 7;

    #pragma unroll 1
    for (int k0 = 0; k0 < K; k0 += 64) {
        __syncthreads();   // previous iter's ds_reads done before overwrite
        #pragma unroll
        for (int r = 0; r < 4; ++r) {            // A: 128 rows x 64 cols
            int row = r * 32 + srow;
            int lc  = schunk ^ (row & 7);        // logical chunk staged into this phys slot
            async16(Ap + (long)(aRow0 + row) * sA + k0 + lc * 8,
                    lsA + (r * 32 + wid * 8) * 64);
        }
        #pragma unroll
        for (int r = 0; r < 6; ++r) {            // B: 3 gates x 64 cols x 64 k
            int brow = r * 32 + srow;            // 0..191
            int lc   = schunk ^ (brow & 7);
            async16(Wp + (long)((brow >> 6) * 1024 + n0 + (brow & 63)) * sW + k0 + lc * 8,
                    lsB + (r * 32 + wid * 8) * 64);
        }
        __syncthreads();   // drains vmcnt (global_load_lds) + all waves arrived
        #pragma unroll
        for (int ks = 0; ks < 4; ++ks) {
            int pc = (((ks * 2 + hi) ^ l7)) * 8;     // swizzled chunk, in shorts
            bf16_8 a0 = *(const bf16_8*)(lsA + (wm * 64 +      l31) * 64 + pc);
            bf16_8 a1 = *(const bf16_8*)(lsA + (wm * 64 + 32 + l31) * 64 + pc);
            bf16_8 br = *(const bf16_8*)(lsB + (        wn * 32 + l31) * 64 + pc);
            bf16_8 bz = *(const bf16_8*)(lsB + ( 64 +   wn * 32 + l31) * 64 + pc);
            bf16_8 bn = *(const bf16_8*)(lsB + (128 +   wn * 32 + l31) * 64 + pc);
            acc[0][0]  = __builtin_amdgcn_mfma_f32_32x32x16_bf16(a0, br, acc[0][0], 0, 0, 0);
            acc[0][1]  = __builtin_amdgcn_mfma_f32_32x32x16_bf16(a1, br, acc[0][1], 0, 0, 0);
            acc[1][0]  = __builtin_amdgcn_mfma_f32_32x32x16_bf16(a0, bz, acc[1][0], 0, 0, 0);
            acc[1][1]  = __builtin_amdgcn_mfma_f32_32x32x16_bf16(a1, bz, acc[1][1], 0, 0, 0);
            acc[QN][0] = __builtin_amdgcn_mfma_f32_32x32x16_bf16(a0, bn, acc[QN][0], 0, 0, 0);
            acc[QN][1] = __builtin_amdgcn_mfma_f32_32x32x16_bf16(a1, bn, acc[QN][1], 0, 0, 0);
        }
    }
}

// h_new = (1-z)*tanh(gi_n + r*gh_n') + z*h_prev
template<int KIH, int KHH, bool USE_E, bool OUT_F32>
__global__ __launch_bounds__(256, 2)
void gru_step(const __bf16* __restrict__ Aih, long sAih,
              const __bf16* __restrict__ Wih,          // bf16, stride 1088
              const __bf16* __restrict__ Ahh,          // bf16, stride 1088
              const __bf16* __restrict__ Whh,          // bf16, stride 1024
              const float*  __restrict__ E,            // 100 x 3072 fp32 (includes b_ih)
              const int*    __restrict__ ids,
              const float*  __restrict__ bih,
              const float*  __restrict__ bhh,
              const __bf16* __restrict__ hprev,        // stride 1088, null for step0
              void* __restrict__ outp, long sOut)
{
    __shared__ __bf16 lsA[128 * 64];   // 16 KB
    __shared__ __bf16 lsB[192 * 64];   // 24 KB
    const int tid  = threadIdx.x;
    const int lane = tid & 63, wid = tid >> 6;
    const int wm = wid >> 1, wn = wid & 1;
    const int l31 = lane & 31, hi = lane >> 5;
    const int m0 = blockIdx.y * 128;       // buoy-row base
    const int n0 = blockIdx.x * 64;        // h-col base

    f32_16 acc[4][2];
    #pragma unroll
    for (int q = 0; q < 4; ++q)
        #pragma unroll
        for (int mt = 0; mt < 2; ++mt) acc[q][mt] = (f32_16)(0.0f);

    phase_loop<2, KIH>(Aih, sAih, m0, Wih, 1088, n0, lsA, lsB, acc, tid);
    if (KHH > 0)
        phase_loop<3, KHH>(Ahh, 1088, m0, Whh, 1024, n0, lsA, lsB, acc, tid);

    // ---- epilogue: gates ----
    const int col = n0 + wn * 32 + l31;            // 0..1023
    const float bhr = bhh[col], bhz = bhh[1024 + col], bhn = bhh[2048 + col];
    float cir = 0.f, ciz = 0.f, cin = 0.f;
    if (!USE_E) { cir = bih[col]; ciz = bih[1024 + col]; cin = bih[2048 + col]; }

    #pragma unroll
    for (int mt = 0; mt < 2; ++mt) {
        const int rowb = m0 + wm * 64 + mt * 32 + 4 * hi;
        #pragma unroll
        for (int reg = 0; reg < 16; ++reg) {
            const int row = rowb + (reg & 3) + 8 * (reg >> 2);   // C/D layout (m101-verified)
            float er = cir, ez = ciz, en = cin;
            if (USE_E) {
                const float* Ep = E + (long)ids[row] * 3072 + col;
                er = Ep[0]; ez = Ep[1024]; en = Ep[2048];
            }
            const float r  = sigm(acc[0][mt][reg] + er + bhr);
            const float z  = sigm(acc[1][mt][reg] + ez + bhz);
            const float nn = tanh_f(acc[2][mt][reg] + en + r * (acc[3][mt][reg] + bhn));
            float hp = 0.f;
            if (KHH > 0) hp = (float)hprev[(long)row * 1088 + col];
            const float h = (1.f - z) * nn + z * hp;
            if (OUT_F32) ((float*)outp)[(long)row * sOut + col] = h;
            else        ((__bf16*)outp)[(long)row * sOut + col] = (__bf16)h;
        }
    }
}

// E[e][j] = b_ih[j] + sum_k emb[e,k]*W_ih[j][64+k], all fp32. Grid (10 e-tiles, 12 j-tiles).
#define ETILE 10
__global__ void compute_E(const float* __restrict__ emb, const float* __restrict__ Wih,
                          const float* __restrict__ bih, float* __restrict__ E)
{
    __shared__ float semb[ETILE * 1024];   // 40 KB
    const int e0 = blockIdx.x * ETILE;
    const int j  = blockIdx.y * 256 + threadIdx.x;     // 0..3071
    for (int i = threadIdx.x; i < ETILE * 1024; i += 256)
        semb[i] = emb[(long)(e0 + (i >> 10)) * 1024 + (i & 1023)];
    __syncthreads();
    const float* wp = Wih + (long)j * 1088 + 64;
    float a[ETILE];
    const float b = bih[j];
    #pragma unroll
    for (int t = 0; t < ETILE; ++t) a[t] = b;
    for (int k = 0; k < 1024; k += 4) {
        const float4 w = *(const float4*)(wp + k);
        #pragma unroll
        for (int t = 0; t < ETILE; ++t) {
            const float* se = semb + t * 1024 + k;
            a[t] += se[0] * w.x + se[1] * w.y + se[2] * w.z + se[3] * w.w;
        }
    }
    #pragma unroll
    for (int t = 0; t < ETILE; ++t) E[(long)(e0 + t) * 3072 + j] = a[t];
}

// OBS[row][t*64+c] = bf16(obs[row][t][c]) for t=0..2; X0 pad=obs1, X1 pad=obs2.
__global__ void build_obs(const float* __restrict__ obs, __bf16* __restrict__ OBS,
                          __bf16* __restrict__ X0, __bf16* __restrict__ X1)
{
    const int q = blockIdx.x * 256 + threadIdx.x;      // 0 .. 16384*48-1
    const int row = q / 48, w = (q % 48) * 4;          // w in [0,192)
    const float4 v = *(const float4*)(obs + (long)row * 512 + w);
    bf16_4 b; b[0] = (__bf16)v.x; b[1] = (__bf16)v.y; b[2] = (__bf16)v.z; b[3] = (__bf16)v.w;
    *(bf16_4*)(OBS + (long)row * 192 + w) = b;
    if (w >= 64 && w < 128) *(bf16_4*)(X0 + (long)row * 1088 + 1024 + (w - 64))  = b;
    if (w >= 128)           *(bf16_4*)(X1 + (long)row * 1088 + 1024 + (w - 128)) = b;
}

__global__ void cast_f32_bf16(const float* __restrict__ s, __bf16* __restrict__ d, int n4)
{
    const int i = blockIdx.x * 256 + threadIdx.x;
    if (i < n4) {
        const float4 v = ((const float4*)s)[i];
        bf16_4 b; b[0] = (__bf16)v.x; b[1] = (__bf16)v.y; b[2] = (__bf16)v.z; b[3] = (__bf16)v.w;
        ((bf16_4*)d)[i] = b;
    }
}

extern "C" void kernel_launch(void* const* d_in, const int* in_sizes, int n_in,
                              void* d_out, int out_size, void* d_ws, size_t ws_size,
                              hipStream_t stream)
{
    const float* obs = (const float*)d_in[0];
    const int*   ids = (const int*)  d_in[1];
    const float* emb = (const float*)d_in[2];
    const float* Wih = (const float*)d_in[3];
    const float* Whh = (const float*)d_in[4];
    const float* bih = (const float*)d_in[5];
    const float* bhh = (const float*)d_in[6];
    float* out = (float*)d_out;

    const size_t MB = 1 << 20;
    const size_t XB = (size_t)NBUOY * 1088 * 2;        // 35,651,584
    const size_t NEEDED = 21 * MB + 3 * XB;            // ~123 MB
    if (ws_size < NEEDED) return;                      // diagnosable: absmax stays 0.734375

    char* ws = (char*)d_ws;
    float*  E   = (float*) ws;                         // 1.23 MB used (2 MB slot)
    __bf16* Wb  = (__bf16*)(ws + 2 * MB);              // 3072x1088 bf16 (6.7 MB, 7 MB slot)
    __bf16* Ub  = (__bf16*)(ws + 9 * MB);              // 3072x1024 bf16 (6 MB slot)
    __bf16* OBS = (__bf16*)(ws + 15 * MB);             // 16384x192 bf16 (6 MB slot)
    __bf16* X0  = (__bf16*)(ws + 21 * MB);
    __bf16* X1  = (__bf16*)(ws + 21 * MB + XB);
    __bf16* X2  = (__bf16*)(ws + 21 * MB + 2 * XB);

    dim3 blk(256);
    dim3 gridG(HID / 64, NBUOY / 128);                 // x = h-cols (16), y = buoy rows (128)

    cast_f32_bf16<<<(3072 * 1088 / 4 + 255) / 256, blk, 0, stream>>>(Wih, Wb, 3072 * 1088 / 4);
    cast_f32_bf16<<<(3072 * 1024 / 4 + 255) / 256, blk, 0, stream>>>(Whh, Ub, 3072 * 1024 / 4);
    build_obs<<<NBUOY * 48 / 256, blk, 0, stream>>>(obs, OBS, X0, X1);
    compute_E<<<dim3(10, 12), blk, 0, stream>>>(emb, Wih, bih, E);

    // step 0: x=[obs0|id_emb], h=0  -> h0 in X0
    gru_step<64, 0, true, false><<<gridG, blk, 0, stream>>>(
        OBS + 0, 192, Wb, nullptr, Ub, E, ids, bih, bhh, nullptr, X0, 1088);
    // step 1: x=[obs1|id_emb], h=h0 -> h1 in X1
    gru_step<64, 1024, true, false><<<gridG, blk, 0, stream>>>(
        OBS + 64, 192, Wb, X0, Ub, E, ids, bih, bhh, X0, X1, 1088);
    // step 2: x=[obs2|id_emb], h=h1 -> h2 in X2
    gru_step<64, 1024, true, false><<<gridG, blk, 0, stream>>>(
        OBS + 128, 192, Wb, X1, Ub, E, ids, bih, bhh, X1, X2, 1088);
    // step 3: x=[h0|obs1] (=X0, pads hold obs1), h=h2 -> h3 in X1 (X1 pads already obs2)
    gru_step<1088, 1024, false, false><<<gridG, blk, 0, stream>>>(
        X0, 1088, Wb, X2, Ub, nullptr, ids, bih, bhh, X2, X1, 1088);
    // step 4: x=[h3|obs2] (=X1), h=h3 -> fp32 d_out
    gru_step<1088, 1024, false, true><<<gridG, blk, 0, stream>>>(
        X1, 1088, Wb, X1, Ub, nullptr, ids, bih, bhh, X1, out, 1024);
}